// Round 8
// baseline (337.117 us; speedup 1.0000x reference)
//
#include <hip/hip_runtime.h>
#include <math.h>

#define NB_PER_BLOCK 16   // batches per 256-thread block
#define ROWSTRIDE 20      // A-row stride in LDS floats (16 data + 4 pad)
#define MATSTRIDE 644     // per-batch stride (32*20 + 4): skews batches across banks

// phase 1: 16 lanes/batch scan 128 occupancy ints -> sorted occupied-k lists.
// phase 2: cooperative gather, 4 lanes per (batch,A-row), one dwordx4 per 64B
//          line touch. R7 measured 287us = MLP-bound: 12 waves x ~8 in-flight
//          = 96 outstanding lines / ~200cy L2 latency = 0.48 lines/cy < 1/cy
//          pipe ceiling. Fix: TWO independent 16-deep acc chains, fully
//          unrolled -> ~2-3x in-flight per wave; __launch_bounds__(256,3)
//          lets VGPR grow to ~170 without occupancy loss (LDS caps 12 waves).
// phase 3: 8-lane-group LU with implicit partial pivoting (lexicographic
//          tie-break). log|det| = sum log|pivot|; parity = (#neg + inversions).
// output:  planar complex: out[b] = re, out[B+b] = im (verified R6).

__global__ __launch_bounds__(256, 3) void backflow_kernel(
    const int* __restrict__ nocc,   // (B,128) int32 0/1
    const float* __restrict__ W,    // (128,2048) f32 row-major
    float* __restrict__ out,        // planar: [B re][B im]
    int B)
{
    __shared__ int lists[NB_PER_BLOCK][33];
    __shared__ float amat[NB_PER_BLOCK * MATSTRIDE];   // ~41.2 KB

    const int tid = threadIdx.x;

    // ---------------- phase 1: occupancy -> k lists ----------------
    {
        const int bib1 = tid >> 4;                 // 0..15
        const int l16  = tid & 15;
        int batch1 = blockIdx.x * NB_PER_BLOCK + bib1;
        if (batch1 >= B) batch1 = B - 1;
        const int4* np = reinterpret_cast<const int4*>(nocc + (size_t)batch1 * 128 + l16 * 8);
        int4 v0 = np[0];
        int4 v1 = np[1];
        unsigned nib = 0;
        nib |= (v0.x != 0) ? 1u   : 0u;
        nib |= (v0.y != 0) ? 2u   : 0u;
        nib |= (v0.z != 0) ? 4u   : 0u;
        nib |= (v0.w != 0) ? 8u   : 0u;
        nib |= (v1.x != 0) ? 16u  : 0u;
        nib |= (v1.y != 0) ? 32u  : 0u;
        nib |= (v1.z != 0) ? 64u  : 0u;
        nib |= (v1.w != 0) ? 128u : 0u;
        const int cnt = __popc(nib);
        int incl = cnt;
        const int seg = l16 & 7;
        #pragma unroll
        for (int d = 1; d < 8; d <<= 1) {
            int t = __shfl_up(incl, d, 8);
            if (seg >= d) incl += t;
        }
        int pos = ((l16 >> 3) << 4) + (incl - cnt);
        const int k0 = l16 * 8;
        #pragma unroll
        for (int b = 0; b < 8; b++) {
            if (nib & (1u << b)) lists[bib1][pos++] = k0 + b;
        }
    }
    __syncthreads();

    // ---------------- phase 2: cooperative gather (4 lanes per A-row) ----------------
    {
        const int q = tid & 3;          // quarter within row
        const int G = tid >> 2;         // row-group 0..63
        #pragma unroll 1
        for (int p = 0; p < 8; p++) {
            const int rowflat = p * 64 + G;        // 0..511 = bib*32 + ridx
            const int bib2 = rowflat >> 5;
            const int ridx = rowflat & 31;         // 0..15 up, 16..31 dn
            const int m2 = ridx >> 4;
            const int r = lists[bib2][ridx] - (m2 << 6);
            const float* wp = W + r * 32 + m2 * 16 + q * 4;
            // two independent 16-deep chains -> ~32 loads in flight
            float4 accA = {0.f, 0.f, 0.f, 0.f};
            float4 accB = {0.f, 0.f, 0.f, 0.f};
            #pragma unroll
            for (int t = 0; t < 16; t++) {
                const int kA = lists[bib2][t];
                const int kB = lists[bib2][t + 16];
                const float4 vA = *reinterpret_cast<const float4*>(wp + (size_t)kA * 2048);
                const float4 vB = *reinterpret_cast<const float4*>(wp + (size_t)kB * 2048);
                accA.x += vA.x; accA.y += vA.y; accA.z += vA.z; accA.w += vA.w;
                accB.x += vB.x; accB.y += vB.y; accB.z += vB.z; accB.w += vB.w;
            }
            float4 acc;
            acc.x = accA.x + accB.x; acc.y = accA.y + accB.y;
            acc.z = accA.z + accB.z; acc.w = accA.w + accB.w;
            *reinterpret_cast<float4*>(&amat[bib2 * MATSTRIDE + ridx * ROWSTRIDE + q * 4]) = acc;
        }
    }
    __syncthreads();

    // ---------------- phase 3: LU, implicit partial pivoting ----------------
    const int lane = tid & 63;
    const int wave = tid >> 6;
    const int g    = lane >> 3;         // matrix group in wave 0..7
    const int s8   = lane & 7;          // lane in group
    const int bw   = g >> 1;            // batch in wave 0..3
    const int m    = g & 1;             // 0 = up, 1 = dn
    const int bib  = (wave << 2) + bw;
    int batch = blockIdx.x * NB_PER_BLOCK + bib;
    const bool valid = (batch < B);
    if (batch >= B) batch = B - 1;

    float a0[16], a1[16];
    {
        const float* row0 = &amat[bib * MATSTRIDE + (m * 16 + s8) * ROWSTRIDE];
        const float* row1 = row0 + 8 * ROWSTRIDE;
        #pragma unroll
        for (int qq = 0; qq < 4; qq++) {
            float4 v0 = *reinterpret_cast<const float4*>(row0 + qq * 4);
            float4 v1 = *reinterpret_cast<const float4*>(row1 + qq * 4);
            a0[qq*4+0] = v0.x; a0[qq*4+1] = v0.y; a0[qq*4+2] = v0.z; a0[qq*4+3] = v0.w;
            a1[qq*4+0] = v1.x; a1[qq*4+1] = v1.y; a1[qq*4+2] = v1.z; a1[qq*4+3] = v1.w;
        }
    }

    unsigned active = 0xffffu;
    int inv = 0;
    float myd0 = 1.f, myd1 = 1.f;

    #pragma unroll
    for (int k = 0; k < 16; k++) {
        const unsigned act0 = (active >> s8) & 1u;
        const unsigned act1 = (active >> (s8 + 8)) & 1u;
        float av = act0 ? fabsf(a0[k]) : -1.f;
        int idx = s8;
        {
            float av1 = act1 ? fabsf(a1[k]) : -1.f;
            if (av1 > av) { av = av1; idx = s8 + 8; }
        }
        #pragma unroll
        for (int d = 1; d < 8; d <<= 1) {
            float ov = __shfl_xor(av, d, 8);
            int   oi = __shfl_xor(idx, d, 8);
            if (ov > av || (ov == av && oi < idx)) { av = ov; idx = oi; }
        }
        const int p = idx;
        const int plane = p & 7;
        const bool phi = (p & 8) != 0;
        float psel = phi ? a1[k] : a0[k];
        const float pk = __shfl(psel, plane, 8);
        const float rcp = 1.0f / pk;

        if (s8 == p)     myd0 = pk;
        if (s8 + 8 == p) myd1 = pk;
        inv += __popc(active & ((1u << p) - 1u));
        active &= ~(1u << p);

        const float f0 = (act0 && s8 != p)       ? a0[k] * rcp : 0.f;
        const float f1 = (act1 && (s8 + 8) != p) ? a1[k] * rcp : 0.f;

        #pragma unroll
        for (int j = k + 1; j < 16; j++) {
            float sel = phi ? a1[j] : a0[j];
            float pv = __shfl(sel, plane, 8);
            a0[j] = fmaf(-f0, pv, a0[j]);
            a1[j] = fmaf(-f1, pv, a1[j]);
        }
    }

    float ld = logf(fabsf(myd0)) + logf(fabsf(myd1));
    int ng = ((myd0 < 0.f) ? 1 : 0) + ((myd1 < 0.f) ? 1 : 0);
    #pragma unroll
    for (int d = 1; d < 8; d <<= 1) {
        ld += __shfl_xor(ld, d, 8);
        ng += __shfl_xor(ng, d, 8);
    }
    const int neg = (ng + inv) & 1;

    const float ld_o  = __shfl_xor(ld, 8, 16);
    const int   neg_o = __shfl_xor(neg, 8, 16);

    if ((lane & 15) == 0 && valid) {
        out[batch]     = ld + ld_o;                                      // re plane
        out[B + batch] = 3.14159265358979323846f * (float)(neg + neg_o); // im plane
    }
}

extern "C" void kernel_launch(void* const* d_in, const int* in_sizes, int n_in,
                              void* d_out, int out_size, void* d_ws, size_t ws_size,
                              hipStream_t stream) {
    const int* nocc = (const int*)d_in[0];
    const float* W  = (const float*)d_in[1];
    float* out = (float*)d_out;
    const int B = in_sizes[0] / 128;                      // 65536
    const int blocks = (B + NB_PER_BLOCK - 1) / NB_PER_BLOCK;  // 4096
    backflow_kernel<<<blocks, 256, 0, stream>>>(nocc, W, out, B);
}

// Round 9
// 321.208 us; speedup vs baseline: 1.0495x; 1.0495x over previous
//
#include <hip/hip_runtime.h>
#include <math.h>

#define NB_PER_BLOCK 16   // batches per 256-thread block
#define ROWSTRIDE 20      // A-row stride in LDS floats (16 data + 4 pad)
#define MATSTRIDE 644     // per-batch stride (32*20 + 4): skews batches across banks

// phase 1: 16 lanes/batch scan 128 occupancy ints -> sorted occupied-k lists.
// phase 2: cooperative gather, 4 lanes per (batch,A-row), one dwordx4 per 64B
//          line touch. bib2 (and hence the k-list) is wave-uniform
//          [bib2 = 2p + (wave>>1)], so k-offsets are readfirstlane'd to the
//          scalar pipe (kills per-lane address VALU), and loads are issued in
//          STRUCTURAL 16-deep batches (float4 v[16]) to force a wide MLP
//          window — R8 proved the compiler won't widen it from hints
//          (VGPR stayed 68).
// phase 3: 8-lane-group LU with implicit partial pivoting (lexicographic
//          tie-break). log|det| = sum log|pivot|; parity = (#neg + inversions).
// output:  planar complex: out[b] = re, out[B+b] = im (verified R6).

__global__ __launch_bounds__(256, 3) void backflow_kernel(
    const int* __restrict__ nocc,   // (B,128) int32 0/1
    const float* __restrict__ W,    // (128,2048) f32 row-major
    float* __restrict__ out,        // planar: [B re][B im]
    int B)
{
    __shared__ int lists[NB_PER_BLOCK][33];
    __shared__ float amat[NB_PER_BLOCK * MATSTRIDE];   // ~41.2 KB

    const int tid = threadIdx.x;

    // ---------------- phase 1: occupancy -> k lists ----------------
    {
        const int bib1 = tid >> 4;                 // 0..15
        const int l16  = tid & 15;
        int batch1 = blockIdx.x * NB_PER_BLOCK + bib1;
        if (batch1 >= B) batch1 = B - 1;
        const int4* np = reinterpret_cast<const int4*>(nocc + (size_t)batch1 * 128 + l16 * 8);
        int4 v0 = np[0];
        int4 v1 = np[1];
        unsigned nib = 0;
        nib |= (v0.x != 0) ? 1u   : 0u;
        nib |= (v0.y != 0) ? 2u   : 0u;
        nib |= (v0.z != 0) ? 4u   : 0u;
        nib |= (v0.w != 0) ? 8u   : 0u;
        nib |= (v1.x != 0) ? 16u  : 0u;
        nib |= (v1.y != 0) ? 32u  : 0u;
        nib |= (v1.z != 0) ? 64u  : 0u;
        nib |= (v1.w != 0) ? 128u : 0u;
        const int cnt = __popc(nib);
        int incl = cnt;
        const int seg = l16 & 7;
        #pragma unroll
        for (int d = 1; d < 8; d <<= 1) {
            int t = __shfl_up(incl, d, 8);
            if (seg >= d) incl += t;
        }
        int pos = ((l16 >> 3) << 4) + (incl - cnt);
        const int k0 = l16 * 8;
        #pragma unroll
        for (int b = 0; b < 8; b++) {
            if (nib & (1u << b)) lists[bib1][pos++] = k0 + b;
        }
    }
    __syncthreads();

    // ---------------- phase 2: cooperative gather (4 lanes per A-row) ----------------
    {
        const int q = tid & 3;          // quarter within row
        const int G = tid >> 2;         // row-group 0..63
        #pragma unroll 1
        for (int p = 0; p < 8; p++) {
            const int rowflat = p * 64 + G;        // 0..511 = bib*32 + ridx
            const int bib2 = rowflat >> 5;         // wave-uniform: 2p + (wave>>1)
            const int ridx = rowflat & 31;         // 0..15 up, 16..31 dn
            const int m2 = ridx >> 4;
            const int r = lists[bib2][ridx] - (m2 << 6);
            const char* wp = (const char*)(W + r * 32 + m2 * 16 + q * 4);  // loop-invariant lane addr

            // k-list as scalar byte offsets (k * 2048 floats * 4B = k << 13)
            int ks[32];
            #pragma unroll
            for (int t = 0; t < 32; t++)
                ks[t] = __builtin_amdgcn_readfirstlane(lists[bib2][t]) << 13;

            float4 acc = {0.f, 0.f, 0.f, 0.f};
            #pragma unroll
            for (int h = 0; h < 2; h++) {
                float4 v[16];                       // structural 16-deep load window
                #pragma unroll
                for (int t = 0; t < 16; t++)
                    v[t] = *reinterpret_cast<const float4*>(wp + ks[h * 16 + t]);
                #pragma unroll
                for (int t = 0; t < 16; t++) {      // t-ascending: same order as R7
                    acc.x += v[t].x; acc.y += v[t].y; acc.z += v[t].z; acc.w += v[t].w;
                }
            }
            *reinterpret_cast<float4*>(&amat[bib2 * MATSTRIDE + ridx * ROWSTRIDE + q * 4]) = acc;
        }
    }
    __syncthreads();

    // ---------------- phase 3: LU, implicit partial pivoting ----------------
    const int lane = tid & 63;
    const int wave = tid >> 6;
    const int g    = lane >> 3;         // matrix group in wave 0..7
    const int s8   = lane & 7;          // lane in group
    const int bw   = g >> 1;            // batch in wave 0..3
    const int m    = g & 1;             // 0 = up, 1 = dn
    const int bib  = (wave << 2) + bw;
    int batch = blockIdx.x * NB_PER_BLOCK + bib;
    const bool valid = (batch < B);
    if (batch >= B) batch = B - 1;

    float a0[16], a1[16];
    {
        const float* row0 = &amat[bib * MATSTRIDE + (m * 16 + s8) * ROWSTRIDE];
        const float* row1 = row0 + 8 * ROWSTRIDE;
        #pragma unroll
        for (int qq = 0; qq < 4; qq++) {
            float4 v0 = *reinterpret_cast<const float4*>(row0 + qq * 4);
            float4 v1 = *reinterpret_cast<const float4*>(row1 + qq * 4);
            a0[qq*4+0] = v0.x; a0[qq*4+1] = v0.y; a0[qq*4+2] = v0.z; a0[qq*4+3] = v0.w;
            a1[qq*4+0] = v1.x; a1[qq*4+1] = v1.y; a1[qq*4+2] = v1.z; a1[qq*4+3] = v1.w;
        }
    }

    unsigned active = 0xffffu;
    int inv = 0;
    float myd0 = 1.f, myd1 = 1.f;

    #pragma unroll
    for (int k = 0; k < 16; k++) {
        const unsigned act0 = (active >> s8) & 1u;
        const unsigned act1 = (active >> (s8 + 8)) & 1u;
        float av = act0 ? fabsf(a0[k]) : -1.f;
        int idx = s8;
        {
            float av1 = act1 ? fabsf(a1[k]) : -1.f;
            if (av1 > av) { av = av1; idx = s8 + 8; }
        }
        #pragma unroll
        for (int d = 1; d < 8; d <<= 1) {
            float ov = __shfl_xor(av, d, 8);
            int   oi = __shfl_xor(idx, d, 8);
            if (ov > av || (ov == av && oi < idx)) { av = ov; idx = oi; }
        }
        const int p = idx;
        const int plane = p & 7;
        const bool phi = (p & 8) != 0;
        float psel = phi ? a1[k] : a0[k];
        const float pk = __shfl(psel, plane, 8);
        const float rcp = 1.0f / pk;

        if (s8 == p)     myd0 = pk;
        if (s8 + 8 == p) myd1 = pk;
        inv += __popc(active & ((1u << p) - 1u));
        active &= ~(1u << p);

        const float f0 = (act0 && s8 != p)       ? a0[k] * rcp : 0.f;
        const float f1 = (act1 && (s8 + 8) != p) ? a1[k] * rcp : 0.f;

        #pragma unroll
        for (int j = k + 1; j < 16; j++) {
            float sel = phi ? a1[j] : a0[j];
            float pv = __shfl(sel, plane, 8);
            a0[j] = fmaf(-f0, pv, a0[j]);
            a1[j] = fmaf(-f1, pv, a1[j]);
        }
    }

    float ld = logf(fabsf(myd0)) + logf(fabsf(myd1));
    int ng = ((myd0 < 0.f) ? 1 : 0) + ((myd1 < 0.f) ? 1 : 0);
    #pragma unroll
    for (int d = 1; d < 8; d <<= 1) {
        ld += __shfl_xor(ld, d, 8);
        ng += __shfl_xor(ng, d, 8);
    }
    const int neg = (ng + inv) & 1;

    const float ld_o  = __shfl_xor(ld, 8, 16);
    const int   neg_o = __shfl_xor(neg, 8, 16);

    if ((lane & 15) == 0 && valid) {
        out[batch]     = ld + ld_o;                                      // re plane
        out[B + batch] = 3.14159265358979323846f * (float)(neg + neg_o); // im plane
    }
}

extern "C" void kernel_launch(void* const* d_in, const int* in_sizes, int n_in,
                              void* d_out, int out_size, void* d_ws, size_t ws_size,
                              hipStream_t stream) {
    const int* nocc = (const int*)d_in[0];
    const float* W  = (const float*)d_in[1];
    float* out = (float*)d_out;
    const int B = in_sizes[0] / 128;                      // 65536
    const int blocks = (B + NB_PER_BLOCK - 1) / NB_PER_BLOCK;  // 4096
    backflow_kernel<<<blocks, 256, 0, stream>>>(nocc, W, out, B);
}

// Round 10
// 320.869 us; speedup vs baseline: 1.0506x; 1.0011x over previous
//
#include <hip/hip_runtime.h>
#include <math.h>

#define NB_PER_BLOCK 16   // batches per 256-thread block
#define RB 8              // batches per round (2 rounds) -> halves amat -> 2x occupancy
#define ROWSTRIDE 20      // A-row stride in LDS floats (16 data + 4 pad)
#define MATSTRIDE 644     // per-batch stride (32*20 + 4): skews batches across banks

// R7-R9 plateau at ~285us across three phase-2 variants => either (a) not
// enough outstanding L1-misses (12 waves, compiler pins per-wave window) or
// (b) hard ~2cy/line per-CU miss-pipe. This round discriminates: amat is cut
// to 8 batches (20.6 KB; total LDS 22.7 KB) and the work done in two
// phase2/phase3 rounds -> 6 blocks = 24 waves/CU (launch_bounds(256,6),
// VGPR 76 <= 85 budget). Gather body identical to R9 (scalarized k-offsets,
// 16-deep structural window). If latency-bound: ~170-210us; if pipe-bound:
// neutral and the floor is structural.
// output: planar complex: out[b] = re, out[B+b] = im (verified R6).

__global__ __launch_bounds__(256, 6) void backflow_kernel(
    const int* __restrict__ nocc,   // (B,128) int32 0/1
    const float* __restrict__ W,    // (128,2048) f32 row-major
    float* __restrict__ out,        // planar: [B re][B im]
    int B)
{
    __shared__ int lists[NB_PER_BLOCK][33];
    __shared__ float amat[RB * MATSTRIDE];   // 20.6 KB

    const int tid = threadIdx.x;

    // ---------------- phase 1: occupancy -> k lists (all 16 batches) ----------------
    {
        const int bib1 = tid >> 4;                 // 0..15
        const int l16  = tid & 15;
        int batch1 = blockIdx.x * NB_PER_BLOCK + bib1;
        if (batch1 >= B) batch1 = B - 1;
        const int4* np = reinterpret_cast<const int4*>(nocc + (size_t)batch1 * 128 + l16 * 8);
        int4 v0 = np[0];
        int4 v1 = np[1];
        unsigned nib = 0;
        nib |= (v0.x != 0) ? 1u   : 0u;
        nib |= (v0.y != 0) ? 2u   : 0u;
        nib |= (v0.z != 0) ? 4u   : 0u;
        nib |= (v0.w != 0) ? 8u   : 0u;
        nib |= (v1.x != 0) ? 16u  : 0u;
        nib |= (v1.y != 0) ? 32u  : 0u;
        nib |= (v1.z != 0) ? 64u  : 0u;
        nib |= (v1.w != 0) ? 128u : 0u;
        const int cnt = __popc(nib);
        int incl = cnt;
        const int seg = l16 & 7;
        #pragma unroll
        for (int d = 1; d < 8; d <<= 1) {
            int t = __shfl_up(incl, d, 8);
            if (seg >= d) incl += t;
        }
        int pos = ((l16 >> 3) << 4) + (incl - cnt);
        const int k0 = l16 * 8;
        #pragma unroll
        for (int b = 0; b < 8; b++) {
            if (nib & (1u << b)) lists[bib1][pos++] = k0 + b;
        }
    }
    __syncthreads();

    const int lane = tid & 63;
    const int wave = tid >> 6;

    #pragma unroll 1
    for (int h = 0; h < 2; h++) {
        // ------------- phase 2 (round h): gather 8 batches, 4 lanes per A-row -------------
        {
            const int q = tid & 3;          // quarter within row
            const int G = tid >> 2;         // row-group 0..63
            #pragma unroll 1
            for (int p = 0; p < 4; p++) {
                const int rowflat = p * 64 + G;        // 0..255 = bloc*32 + ridx
                const int bloc = rowflat >> 5;         // wave-uniform: 2p + (wave>>1)
                const int bib2 = h * RB + bloc;
                const int ridx = rowflat & 31;         // 0..15 up, 16..31 dn
                const int m2 = ridx >> 4;
                const int r = lists[bib2][ridx] - (m2 << 6);
                const char* wp = (const char*)(W + r * 32 + m2 * 16 + q * 4);

                // k-list as scalar byte offsets (k * 2048 floats * 4B = k << 13)
                int ks[32];
                #pragma unroll
                for (int t = 0; t < 32; t++)
                    ks[t] = __builtin_amdgcn_readfirstlane(lists[bib2][t]) << 13;

                float4 acc = {0.f, 0.f, 0.f, 0.f};
                #pragma unroll
                for (int hh = 0; hh < 2; hh++) {
                    float4 v[16];                       // structural 16-deep load window
                    #pragma unroll
                    for (int t = 0; t < 16; t++)
                        v[t] = *reinterpret_cast<const float4*>(wp + ks[hh * 16 + t]);
                    #pragma unroll
                    for (int t = 0; t < 16; t++) {
                        acc.x += v[t].x; acc.y += v[t].y; acc.z += v[t].z; acc.w += v[t].w;
                    }
                }
                *reinterpret_cast<float4*>(&amat[bloc * MATSTRIDE + ridx * ROWSTRIDE + q * 4]) = acc;
            }
        }
        __syncthreads();

        // ------------- phase 3 (round h): LU on 16 matrices, waves 0-1 -------------
        if (wave < 2) {
            const int gg   = wave * 8 + (lane >> 3);   // matrix 0..15
            const int s8   = lane & 7;
            const int bloc = gg >> 1;                  // local batch 0..7
            const int m    = gg & 1;                   // 0 = up, 1 = dn
            int batch = blockIdx.x * NB_PER_BLOCK + h * RB + bloc;
            const bool valid = (batch < B);
            if (batch >= B) batch = B - 1;

            float a0[16], a1[16];
            {
                const float* row0 = &amat[bloc * MATSTRIDE + (m * 16 + s8) * ROWSTRIDE];
                const float* row1 = row0 + 8 * ROWSTRIDE;
                #pragma unroll
                for (int qq = 0; qq < 4; qq++) {
                    float4 v0 = *reinterpret_cast<const float4*>(row0 + qq * 4);
                    float4 v1 = *reinterpret_cast<const float4*>(row1 + qq * 4);
                    a0[qq*4+0] = v0.x; a0[qq*4+1] = v0.y; a0[qq*4+2] = v0.z; a0[qq*4+3] = v0.w;
                    a1[qq*4+0] = v1.x; a1[qq*4+1] = v1.y; a1[qq*4+2] = v1.z; a1[qq*4+3] = v1.w;
                }
            }

            unsigned active = 0xffffu;
            int inv = 0;
            float myd0 = 1.f, myd1 = 1.f;

            #pragma unroll
            for (int k = 0; k < 16; k++) {
                const unsigned act0 = (active >> s8) & 1u;
                const unsigned act1 = (active >> (s8 + 8)) & 1u;
                float av = act0 ? fabsf(a0[k]) : -1.f;
                int idx = s8;
                {
                    float av1 = act1 ? fabsf(a1[k]) : -1.f;
                    if (av1 > av) { av = av1; idx = s8 + 8; }
                }
                #pragma unroll
                for (int d = 1; d < 8; d <<= 1) {
                    float ov = __shfl_xor(av, d, 8);
                    int   oi = __shfl_xor(idx, d, 8);
                    if (ov > av || (ov == av && oi < idx)) { av = ov; idx = oi; }
                }
                const int p = idx;
                const int plane = p & 7;
                const bool phi = (p & 8) != 0;
                float psel = phi ? a1[k] : a0[k];
                const float pk = __shfl(psel, plane, 8);
                const float rcp = 1.0f / pk;

                if (s8 == p)     myd0 = pk;
                if (s8 + 8 == p) myd1 = pk;
                inv += __popc(active & ((1u << p) - 1u));
                active &= ~(1u << p);

                const float f0 = (act0 && s8 != p)       ? a0[k] * rcp : 0.f;
                const float f1 = (act1 && (s8 + 8) != p) ? a1[k] * rcp : 0.f;

                #pragma unroll
                for (int j = k + 1; j < 16; j++) {
                    float sel = phi ? a1[j] : a0[j];
                    float pv = __shfl(sel, plane, 8);
                    a0[j] = fmaf(-f0, pv, a0[j]);
                    a1[j] = fmaf(-f1, pv, a1[j]);
                }
            }

            float ld = logf(fabsf(myd0)) + logf(fabsf(myd1));
            int ng = ((myd0 < 0.f) ? 1 : 0) + ((myd1 < 0.f) ? 1 : 0);
            #pragma unroll
            for (int d = 1; d < 8; d <<= 1) {
                ld += __shfl_xor(ld, d, 8);
                ng += __shfl_xor(ng, d, 8);
            }
            const int neg = (ng + inv) & 1;

            const float ld_o  = __shfl_xor(ld, 8, 16);
            const int   neg_o = __shfl_xor(neg, 8, 16);

            if ((lane & 15) == 0 && valid) {
                out[batch]     = ld + ld_o;                                      // re plane
                out[B + batch] = 3.14159265358979323846f * (float)(neg + neg_o); // im plane
            }
        }
        __syncthreads();   // amat reused by next round
    }
}

extern "C" void kernel_launch(void* const* d_in, const int* in_sizes, int n_in,
                              void* d_out, int out_size, void* d_ws, size_t ws_size,
                              hipStream_t stream) {
    const int* nocc = (const int*)d_in[0];
    const float* W  = (const float*)d_in[1];
    float* out = (float*)d_out;
    const int B = in_sizes[0] / 128;                      // 65536
    const int blocks = (B + NB_PER_BLOCK - 1) / NB_PER_BLOCK;  // 4096
    backflow_kernel<<<blocks, 256, 0, stream>>>(nocc, W, out, B);
}